// Round 6
// baseline (137.026 us; speedup 1.0000x reference)
//
#include <hip/hip_runtime.h>
#include <math.h>

#define QMAXF 127.0f
#define EPSF  1e-8f
#define CIN   256
#define COUT  128
#define HW    3136        // 56*56
#define W_    56
#define NPOOL 3211264     // 32*128*28*28
#define POOL_BLOCKS 1792

typedef unsigned short u16;
typedef unsigned int   u32;
typedef __attribute__((ext_vector_type(8))) short s16x8;
typedef __attribute__((ext_vector_type(4))) float f32x4;

// ws float-index layout
#define WQ_OFF   8        // wqd[256]
#define BF_OFF   264      // b_fold[256]
#define EMAX_OFF 520      // per-channel enc(max) u32[256]
#define EMIN_OFF 776      // per-channel enc(min) u32[256]
#define CS_OFF   1032     // conv_s[128]
#define CSS2_OFF 1160     // s2*conv_s[128]
#define LUT_OFF  1288     // u16[256*256] -> 32768 floats
#define WIMG_OFF 34056    // u16[4][8192] W LDS-images (swizzled) -> 16384 floats
#define A_OFF    50440    // A images u16[1568*4*4096]; REUSED as y f32[1568*8192]
// total = 50440 + 12845056 floats ~= 51.6 MB

__device__ __forceinline__ float qclip(float v) {
    return fminf(fmaxf(v, -128.0f), 127.0f);
}
__device__ __forceinline__ u16 bf16bits(float f) {
    return (u16)(__float_as_uint(f) >> 16);   // exact for small ints
}
__device__ __forceinline__ u32 encf(float f) {
    u32 u = __float_as_uint(f);
    return (u & 0x80000000u) ? ~u : (u | 0x80000000u);
}
__device__ __forceinline__ float decf(u32 k) {
    return __uint_as_float((k & 0x80000000u) ? (k ^ 0x80000000u) : ~k);
}
__device__ __forceinline__ void gload16(const u16* g, u16* l) {
    __builtin_amdgcn_global_load_lds((const __attribute__((address_space(1))) u32*)g,
                                     (__attribute__((address_space(3))) u32*)l,
                                     16, 0, 0);
}

__device__ __forceinline__ void block_max_atomic(float v, float* red, u32* dst) {
    #pragma unroll
    for (int off = 32; off > 0; off >>= 1) v = fmaxf(v, __shfl_xor(v, off));
    const int lane = threadIdx.x & 63, wid = threadIdx.x >> 6;
    if (lane == 0) red[wid] = v;
    __syncthreads();
    if (threadIdx.x == 0) {
        const int nw = blockDim.x >> 6;
        float m = red[0];
        for (int i = 1; i < nw; ++i) m = fmaxf(m, red[i]);
        atomicMax(dst, __float_as_uint(m));
    }
}

// K0w: per-row quant of conv_w -> swizzled bf16 W-images + conv_s; inits
__global__ void k0w(const float* __restrict__ cw, float* __restrict__ ws) {
    const int t = threadIdx.x;
    if (blockIdx.x == COUT) {
        ((u32*)ws)[EMAX_OFF + t] = 0u;
        ((u32*)ws)[EMIN_OFF + t] = 0xFFFFFFFFu;
        if (t < 2) ((u32*)ws)[2 + t] = 0u;   // y-max, pool-max atomic slots
        return;
    }
    __shared__ float red[4];
    const int o = blockIdx.x;
    const float wv = cw[o * CIN + t];
    float v = fabsf(wv);
    #pragma unroll
    for (int off = 32; off > 0; off >>= 1) v = fmaxf(v, __shfl_xor(v, off));
    if ((t & 63) == 0) red[t >> 6] = v;
    __syncthreads();
    const float mx = fmaxf(fmaxf(red[0], red[1]), fmaxf(red[2], red[3]));
    const float s = fmaxf(mx / QMAXF, EPSF);
    const float q = qclip(rintf(wv / s));
    const int ckt = t >> 6, kloc = t & 63, koct = kloc >> 3, klow = kloc & 7;
    ((u16*)(ws + WIMG_OFF))[ckt * 8192 + o * 64 +
                            ((koct + o + (o >> 3)) & 7) * 8 + klow] = bf16bits(q);
    if (t == 0) ws[CS_OFF + o] = s;
}

// K1: per-(b,c)-row min/max of x -> per-channel enc atomics
__global__ void k1_minmax(const float* __restrict__ x, float* __restrict__ ws) {
    __shared__ float red[8];
    const int row = blockIdx.x;                       // 32*256 rows
    const float4* xr = (const float4*)(x + (size_t)row * HW);
    float mx = -3.402823466e38f, mn = 3.402823466e38f;
    for (int i = threadIdx.x; i < HW / 4; i += 256) {
        const float4 v = xr[i];
        mx = fmaxf(mx, fmaxf(fmaxf(v.x, v.y), fmaxf(v.z, v.w)));
        mn = fminf(mn, fminf(fminf(v.x, v.y), fminf(v.z, v.w)));
    }
    #pragma unroll
    for (int off = 32; off > 0; off >>= 1) {
        mx = fmaxf(mx, __shfl_xor(mx, off));
        mn = fminf(mn, __shfl_xor(mn, off));
    }
    if ((threadIdx.x & 63) == 0) {
        red[threadIdx.x >> 6] = mx;
        red[4 + (threadIdx.x >> 6)] = mn;
    }
    __syncthreads();
    if (threadIdx.x == 0) {
        mx = fmaxf(fmaxf(red[0], red[1]), fmaxf(red[2], red[3]));
        mn = fminf(fminf(red[4], red[5]), fminf(red[6], red[7]));
        const int c = row & (CIN - 1);
        atomicMax((u32*)ws + EMAX_OFF + c, encf(mx));
        atomicMin((u32*)ws + EMIN_OFF + c, encf(mn));
    }
}

// K0b: s1 from channel extremes; BN fold + quant; s2 from affine endpoints
__global__ void k0b(const float* __restrict__ g, const float* __restrict__ be,
                    const float* __restrict__ mnp, const float* __restrict__ vr,
                    float* __restrict__ ws) {
    __shared__ float red[4];
    __shared__ float s1sh;
    const int t = threadIdx.x;
    const float cmax = decf(((u32*)ws)[EMAX_OFF + t]);
    const float cmin = decf(((u32*)ws)[EMIN_OFF + t]);
    float v = fmaxf(fabsf(cmax), fabsf(cmin));
    #pragma unroll
    for (int off = 32; off > 0; off >>= 1) v = fmaxf(v, __shfl_xor(v, off));
    if ((t & 63) == 0) red[t >> 6] = v;
    __syncthreads();
    if (t == 0) {
        const float m1 = fmaxf(fmaxf(red[0], red[1]), fmaxf(red[2], red[3]));
        ws[0] = m1;
        s1sh = fmaxf(m1 / QMAXF, EPSF);
    }
    __syncthreads();
    const float s1 = s1sh;
    const float wf = g[t] / sqrtf(vr[t] + 1e-5f);
    const float bf = be[t] - mnp[t] * wf;
    const float sw = fmaxf(fabsf(wf) / QMAXF, EPSF);
    const float q  = qclip(rintf(wf / sw));
    const float wqd = __fmul_rn(q, sw);
    ws[WQ_OFF + t] = wqd;
    ws[BF_OFF + t] = bf;
    const float q1h = qclip(rintf(cmax / s1));
    const float q1l = qclip(rintf(cmin / s1));
    const float xh = __fadd_rn(__fmul_rn(__fmul_rn(q1h, s1), wqd), bf);
    const float xl = __fadd_rn(__fmul_rn(__fmul_rn(q1l, s1), wqd), bf);
    float m2 = fmaxf(fabsf(xh), fabsf(xl));
    __syncthreads();
    #pragma unroll
    for (int off = 32; off > 0; off >>= 1) m2 = fmaxf(m2, __shfl_xor(m2, off));
    if ((t & 63) == 0) red[t >> 6] = m2;
    __syncthreads();
    if (t == 0) ws[1] = fmaxf(fmaxf(red[0], red[1]), fmaxf(red[2], red[3]));
}

// K0L: exact stage-2 quant LUT + CSS2
__global__ void k0L(float* __restrict__ ws) {
    const int c = blockIdx.x;
    const int t = threadIdx.x;
    const float s1 = fmaxf(ws[0] / QMAXF, EPSF);
    const float s2 = fmaxf(ws[1] / QMAXF, EPSF);
    const float wqd = ws[WQ_OFF + c];
    const float bf  = ws[BF_OFF + c];
    const float q1f = (float)(t - 127);
    const float xd  = __fmul_rn(q1f, s1);
    const float x2  = __fadd_rn(__fmul_rn(xd, wqd), bf);
    const float q2  = qclip(rintf(x2 / s2));
    const float a   = fmaxf(q2, 0.0f);
    ((u16*)(ws + LUT_OFF))[(c << 8) + t] = bf16bits(a);
    if (c == 0 && t < COUT)
        ws[CSS2_OFF + t] = __fmul_rn(s2, ws[CS_OFF + t]);
}

// kA: streaming transform x -> A (bf16 ints), written as pre-swizzled LDS images.
// No LDS, no barriers; 16 independent loads in flight per thread.
__global__ __launch_bounds__(256) void kA_xform(const float* __restrict__ x,
                                                float* __restrict__ ws) {
    const int t = threadIdx.x;
    const int b = blockIdx.x / 49, t64 = blockIdx.x % 49;
    const int hw0 = t64 * 64;
    const int pl = t & 63, kh16 = t >> 6;
    const float s1 = fmaxf(ws[0] / QMAXF, EPSF);
    const u16* lut = (const u16*)(ws + LUT_OFF);
    u16* A16 = (u16*)(ws + A_OFF);
    const int swa = ((kh16 * 2 + pl + (pl >> 3)) & 7) * 8;
    const int swb = ((kh16 * 2 + 1 + pl + (pl >> 3)) & 7) * 8;
    #pragma unroll
    for (int ckt = 0; ckt < 4; ++ckt) {
        const int c0 = ckt * 64 + kh16 * 16;
        const float* xb = x + ((size_t)(b * CIN + c0)) * HW + hw0 + pl;
        float xv[16];
        #pragma unroll
        for (int j = 0; j < 16; ++j) xv[j] = xb[j * HW];
        u32 pk[8];
        #pragma unroll
        for (int jj = 0; jj < 8; ++jj) {
            const int q1a = (int)rintf(xv[2 * jj] / s1);       // |x/s1|<=127: no clip
            const int q1b = (int)rintf(xv[2 * jj + 1] / s1);
            const u32 lo = lut[((c0 + 2 * jj) << 8) + 127 + q1a];
            const u32 hi = lut[((c0 + 2 * jj + 1) << 8) + 127 + q1b];
            pk[jj] = lo | (hi << 16);
        }
        u16* slab = A16 + ((((size_t)(b * 49 + t64)) * 4 + ckt) << 12) + pl * 64;
        uint4 v0; v0.x = pk[0]; v0.y = pk[1]; v0.z = pk[2]; v0.w = pk[3];
        uint4 v1; v1.x = pk[4]; v1.y = pk[5]; v1.z = pk[6]; v1.w = pk[7];
        *(uint4*)(slab + swa) = v0;
        *(uint4*)(slab + swb) = v1;
    }
}

// kB: pure bf16-MFMA GEMM. Stages pre-imaged A/W tiles via global_load_lds
// (width 16, linear LDS dest), double-buffered, one barrier per K-step.
// Writes y OVER this block's own A slabs (consumed), + block max -> ws[2].
__global__ __launch_bounds__(256) void kB_gemm(float* __restrict__ ws) {
    __shared__ __align__(16) u16 Xl[2][4096];
    __shared__ __align__(16) u16 Wl[2][8192];
    __shared__ float Css2s[COUT];
    __shared__ float red[4];

    const int t = threadIdx.x;
    const int b = blockIdx.x / 49, t64 = blockIdx.x % 49;
    const int l = t & 63, w = t >> 6;
    const int wc = (w >> 1) * 64;      // wave cout base
    const int wp = (w & 1) * 32;       // wave pixel base

    const u16* A16 = (const u16*)(ws + A_OFF);
    const u16* W16 = (const u16*)(ws + WIMG_OFF);
    const size_t slab0 = ((size_t)(b * 49 + t64)) << 14;   // u16 units (4*4096)

    if (t < COUT) Css2s[t] = ws[CSS2_OFF + t];

    f32x4 acc[4][2];
    #pragma unroll
    for (int m = 0; m < 4; ++m)
        #pragma unroll
        for (int n = 0; n < 2; ++n) acc[m][n] = (f32x4)0.0f;

    const int wvb = (t >> 6) * 512;    // wave-uniform LDS base (u16)
    const int tsrc = t * 8;

    // prologue: stage tile 0 into buf 0
    {
        const u16* sX = A16 + slab0;
        const u16* sW = W16;
        #pragma unroll
        for (int r = 0; r < 2; ++r)
            gload16(sX + tsrc + r * 2048, &Xl[0][wvb + r * 2048]);
        #pragma unroll
        for (int r = 0; r < 4; ++r)
            gload16(sW + tsrc + r * 2048, &Wl[0][wvb + r * 2048]);
    }
    __syncthreads();

    #pragma unroll
    for (int it = 0; it < 4; ++it) {
        const int buf = it & 1;
        if (it < 3) {                   // stage next tile into other buffer
            const u16* sX = A16 + slab0 + (size_t)(it + 1) * 4096;
            const u16* sW = W16 + (it + 1) * 8192;
            #pragma unroll
            for (int r = 0; r < 2; ++r)
                gload16(sX + tsrc + r * 2048, &Xl[buf ^ 1][wvb + r * 2048]);
            #pragma unroll
            for (int r = 0; r < 4; ++r)
                gload16(sW + tsrc + r * 2048, &Wl[buf ^ 1][wvb + r * 2048]);
        }
        #pragma unroll
        for (int ks = 0; ks < 2; ++ks) {
            const int ch = ks * 4 + (l >> 4);
            s16x8 xf[2], wfr[4];
            #pragma unroll
            for (int n = 0; n < 2; ++n) {
                const int pp = wp + n * 16 + (l & 15);
                xf[n] = *(const s16x8*)&Xl[buf][pp * 64 + (((ch + pp + (pp >> 3)) & 7) * 8)];
            }
            #pragma unroll
            for (int m = 0; m < 4; ++m) {
                const int o = wc + m * 16 + (l & 15);
                wfr[m] = *(const s16x8*)&Wl[buf][o * 64 + (((ch + o + (o >> 3)) & 7) * 8)];
            }
            #pragma unroll
            for (int m = 0; m < 4; ++m)
                #pragma unroll
                for (int n = 0; n < 2; ++n)
                    acc[m][n] = __builtin_amdgcn_mfma_f32_16x16x32_bf16(
                                    wfr[m], xf[n], acc[m][n], 0, 0, 0);
        }
        __syncthreads();                // drains vmcnt (gload_lds) + lgkm
    }

    // epilogue: y = int_sum * (s2*conv_s[o]) written over this block's A slabs
    float* yblk = ws + A_OFF + (((size_t)(b * 49 + t64)) << 13);
    float mloc = 0.0f;
    #pragma unroll
    for (int m = 0; m < 4; ++m) {
        #pragma unroll
        for (int n = 0; n < 2; ++n) {
            const int pixl = wp + n * 16 + (l & 15);
            #pragma unroll
            for (int r = 0; r < 4; ++r) {
                const int o = wc + m * 16 + (l >> 4) * 4 + r;
                const float val = __fmul_rn(acc[m][n][r], Css2s[o]);
                yblk[o * 64 + pixl] = val;
                mloc = fmaxf(mloc, fabsf(val));
            }
        }
    }
    block_max_atomic(mloc, red, (u32*)ws + 2);
}

// K4: integer-domain 2x2 average pool over slab-stored y; pooled -> d_out
__global__ void k4_pool(float* __restrict__ ws, float* __restrict__ out) {
    __shared__ float red[4];
    const float s3 = fmaxf(ws[2] / QMAXF, EPSF);
    float mloc = 0.0f;
    const int nq2 = NPOOL / 2;
    for (int pp = blockIdx.x * 256 + threadIdx.x; pp < nq2;
         pp += POOL_BLOCKS * 256) {
        const int j2  = pp % 14;
        const int tmp = pp / 14;
        const int i   = tmp % 28;
        const int bo  = tmp / 28;
        const int b = bo >> 7, o = bo & 127;
        const int p0 = (2 * i) * W_ + 4 * j2;      // %4==0, (p0&63)<=60
        const int p1 = p0 + W_;
        const float* y0 = ws + A_OFF + (((size_t)(b * 49 + (p0 >> 6))) << 13)
                          + (o << 6) + (p0 & 63);
        const float* y1 = ws + A_OFF + (((size_t)(b * 49 + (p1 >> 6))) << 13)
                          + (o << 6) + (p1 & 63);
        const float4 r0 = *(const float4*)y0;
        const float4 r1 = *(const float4*)y1;
        const float q00 = qclip(rintf(r0.x / s3)), q01 = qclip(rintf(r0.y / s3));
        const float q02 = qclip(rintf(r0.z / s3)), q03 = qclip(rintf(r0.w / s3));
        const float q10 = qclip(rintf(r1.x / s3)), q11 = qclip(rintf(r1.y / s3));
        const float q12 = qclip(rintf(r1.z / s3)), q13 = qclip(rintf(r1.w / s3));
        const float p0v = __fmul_rn(__fmul_rn((q00 + q01) + (q10 + q11), 0.25f), s3);
        const float p1v = __fmul_rn(__fmul_rn((q02 + q03) + (q12 + q13), 0.25f), s3);
        float2 pv; pv.x = p0v; pv.y = p1v;
        *(float2*)(out + (size_t)bo * 784 + i * 28 + 2 * j2) = pv;
        mloc = fmaxf(mloc, fmaxf(fabsf(p0v), fabsf(p1v)));
    }
    block_max_atomic(mloc, red, (u32*)ws + 3);
}

// K5: final fake-quant in place + act_s scalar
__global__ void k5_final(float* __restrict__ out, const float* __restrict__ ws) {
    const float s4 = fmaxf(ws[3] / QMAXF, EPSF);
    const int n4 = NPOOL / 4;
    for (int i = blockIdx.x * 256 + threadIdx.x; i < n4; i += 3136 * 256) {
        float4 v = *(float4*)(out + 4 * (size_t)i);
        v.x = __fmul_rn(qclip(rintf(v.x / s4)), s4);
        v.y = __fmul_rn(qclip(rintf(v.y / s4)), s4);
        v.z = __fmul_rn(qclip(rintf(v.z / s4)), s4);
        v.w = __fmul_rn(qclip(rintf(v.w / s4)), s4);
        *(float4*)(out + 4 * (size_t)i) = v;
    }
    if (blockIdx.x == 0 && threadIdx.x == 0) out[NPOOL] = s4;
}

extern "C" void kernel_launch(void* const* d_in, const int* in_sizes, int n_in,
                              void* d_out, int out_size, void* d_ws, size_t ws_size,
                              hipStream_t stream) {
    const float* x     = (const float*)d_in[0];
    const float* gamma = (const float*)d_in[1];
    const float* beta  = (const float*)d_in[2];
    const float* mean  = (const float*)d_in[3];
    const float* var   = (const float*)d_in[4];
    const float* cw    = (const float*)d_in[5];
    float* out = (float*)d_out;
    float* ws  = (float*)d_ws;

    hipLaunchKernelGGL(k0w, dim3(COUT + 1), dim3(256), 0, stream, cw, ws);
    hipLaunchKernelGGL(k1_minmax, dim3(32 * CIN), dim3(256), 0, stream, x, ws);
    hipLaunchKernelGGL(k0b, dim3(1), dim3(256), 0, stream, gamma, beta, mean, var, ws);
    hipLaunchKernelGGL(k0L, dim3(256), dim3(256), 0, stream, ws);
    hipLaunchKernelGGL(kA_xform, dim3(1568), dim3(256), 0, stream, x, ws);
    hipLaunchKernelGGL(kB_gemm, dim3(1568), dim3(256), 0, stream, ws);
    hipLaunchKernelGGL(k4_pool, dim3(POOL_BLOCKS), dim3(256), 0, stream, ws, out);
    hipLaunchKernelGGL(k5_final, dim3(3136), dim3(256), 0, stream, out, ws);
}

// Round 7
// 116.256 us; speedup vs baseline: 1.1787x; 1.1787x over previous
//
#include <hip/hip_runtime.h>
#include <math.h>

#define QMAXF 127.0f
#define EPSF  1e-8f
#define CIN   256
#define COUT  128
#define HW    3136        // 56*56
#define W_    56
#define NPOOL 3211264     // 32*128*28*28
#define POOL_BLOCKS 1792

typedef unsigned short u16;
typedef unsigned int   u32;
typedef __attribute__((ext_vector_type(8))) short s16x8;
typedef __attribute__((ext_vector_type(4))) float f32x4;

// ws float-index layout
#define WQ_OFF   8        // wqd[256] (f32)
#define BF_OFF   264      // b_fold[256]
#define EMAX_OFF 520      // per-channel enc(max) u32[256]
#define EMIN_OFF 776      // per-channel enc(min) u32[256]
#define CS_OFF   1032     // conv_s[128]
#define CSS2_OFF 1160     // s2*conv_s[128]
#define CWB_OFF  1288     // qcw as bf16 u16[128*256] = 16384 float slots
#define LUT_OFF  17672    // u16[256*256]: c,q1+127 -> bf16(relu(q2)) = 32768 floats
#define Y_OFF    50440    // y[32*128*3136] f32  (~51.6 MB total)

__device__ __forceinline__ float qclip(float v) {
    return fminf(fmaxf(v, -128.0f), 127.0f);
}
__device__ __forceinline__ u16 bf16bits(float f) {
    return (u16)(__float_as_uint(f) >> 16);   // exact for small ints
}
__device__ __forceinline__ u32 encf(float f) {
    u32 u = __float_as_uint(f);
    return (u & 0x80000000u) ? ~u : (u | 0x80000000u);
}
__device__ __forceinline__ float decf(u32 k) {
    return __uint_as_float((k & 0x80000000u) ? (k ^ 0x80000000u) : ~k);
}

__device__ __forceinline__ void block_max_atomic(float v, float* red, u32* dst) {
    #pragma unroll
    for (int off = 32; off > 0; off >>= 1) v = fmaxf(v, __shfl_xor(v, off));
    const int lane = threadIdx.x & 63, wid = threadIdx.x >> 6;
    if (lane == 0) red[wid] = v;
    __syncthreads();
    if (threadIdx.x == 0) {
        const int nw = blockDim.x >> 6;
        float m = red[0];
        for (int i = 1; i < nw; ++i) m = fmaxf(m, red[i]);
        atomicMax(dst, __float_as_uint(m));
    }
}

// K0w: per-row quant of conv_w -> bf16 ints + conv_s; extra block inits enc arrays
__global__ void k0w(const float* __restrict__ cw, float* __restrict__ ws) {
    const int t = threadIdx.x;
    if (blockIdx.x == COUT) {
        ((u32*)ws)[EMAX_OFF + t] = 0u;
        ((u32*)ws)[EMIN_OFF + t] = 0xFFFFFFFFu;
        if (t < 2) ((u32*)ws)[2 + t] = 0u;   // y-max, pool-max atomics
        return;
    }
    __shared__ float red[4];
    const int o = blockIdx.x;
    const float wv = cw[o * CIN + t];
    float v = fabsf(wv);
    #pragma unroll
    for (int off = 32; off > 0; off >>= 1) v = fmaxf(v, __shfl_xor(v, off));
    if ((t & 63) == 0) red[t >> 6] = v;
    __syncthreads();
    const float mx = fmaxf(fmaxf(red[0], red[1]), fmaxf(red[2], red[3]));
    const float s = fmaxf(mx / QMAXF, EPSF);
    const float q = qclip(rintf(wv / s));
    ((u16*)(ws + CWB_OFF))[o * CIN + t] = bf16bits(q);
    if (t == 0) ws[CS_OFF + o] = s;
}

// K1: per-(b,c)-row min/max of x -> per-channel enc atomics
__global__ void k1_minmax(const float* __restrict__ x, float* __restrict__ ws) {
    __shared__ float red[8];
    const int row = blockIdx.x;                       // 32*256 rows
    const float4* xr = (const float4*)(x + (size_t)row * HW);
    float mx = -3.402823466e38f, mn = 3.402823466e38f;
    for (int i = threadIdx.x; i < HW / 4; i += 256) {
        const float4 v = xr[i];
        mx = fmaxf(mx, fmaxf(fmaxf(v.x, v.y), fmaxf(v.z, v.w)));
        mn = fminf(mn, fminf(fminf(v.x, v.y), fminf(v.z, v.w)));
    }
    #pragma unroll
    for (int off = 32; off > 0; off >>= 1) {
        mx = fmaxf(mx, __shfl_xor(mx, off));
        mn = fminf(mn, __shfl_xor(mn, off));
    }
    if ((threadIdx.x & 63) == 0) {
        red[threadIdx.x >> 6] = mx;
        red[4 + (threadIdx.x >> 6)] = mn;
    }
    __syncthreads();
    if (threadIdx.x == 0) {
        mx = fmaxf(fmaxf(red[0], red[1]), fmaxf(red[2], red[3]));
        mn = fminf(fminf(red[4], red[5]), fminf(red[6], red[7]));
        const int c = row & (CIN - 1);
        atomicMax((u32*)ws + EMAX_OFF + c, encf(mx));
        atomicMin((u32*)ws + EMIN_OFF + c, encf(mn));
    }
}

// K0b: s1 from channel extremes; BN fold + quant; s2 from per-channel affine endpoints
__global__ void k0b(const float* __restrict__ g, const float* __restrict__ be,
                    const float* __restrict__ mnp, const float* __restrict__ vr,
                    float* __restrict__ ws) {
    __shared__ float red[4];
    __shared__ float s1sh;
    const int t = threadIdx.x;
    const float cmax = decf(((u32*)ws)[EMAX_OFF + t]);
    const float cmin = decf(((u32*)ws)[EMIN_OFF + t]);
    float v = fmaxf(fabsf(cmax), fabsf(cmin));
    #pragma unroll
    for (int off = 32; off > 0; off >>= 1) v = fmaxf(v, __shfl_xor(v, off));
    if ((t & 63) == 0) red[t >> 6] = v;
    __syncthreads();
    if (t == 0) {
        const float m1 = fmaxf(fmaxf(red[0], red[1]), fmaxf(red[2], red[3]));
        ws[0] = m1;
        s1sh = fmaxf(m1 / QMAXF, EPSF);
    }
    __syncthreads();
    const float s1 = s1sh;
    const float wf = g[t] / sqrtf(vr[t] + 1e-5f);
    const float bf = be[t] - mnp[t] * wf;
    const float sw = fmaxf(fabsf(wf) / QMAXF, EPSF);
    const float q  = qclip(rintf(wf / sw));
    const float wqd = __fmul_rn(q, sw);
    ws[WQ_OFF + t] = wqd;
    ws[BF_OFF + t] = bf;
    const float q1h = qclip(rintf(cmax / s1));
    const float q1l = qclip(rintf(cmin / s1));
    const float xh = __fadd_rn(__fmul_rn(__fmul_rn(q1h, s1), wqd), bf);
    const float xl = __fadd_rn(__fmul_rn(__fmul_rn(q1l, s1), wqd), bf);
    float m2 = fmaxf(fabsf(xh), fabsf(xl));
    __syncthreads();
    #pragma unroll
    for (int off = 32; off > 0; off >>= 1) m2 = fmaxf(m2, __shfl_xor(m2, off));
    if ((t & 63) == 0) red[t >> 6] = m2;
    __syncthreads();
    if (t == 0) ws[1] = fmaxf(fmaxf(red[0], red[1]), fmaxf(red[2], red[3]));
}

// K0L: exact LUT for stage-2 quant: lut[c][q1+127] = bf16(relu(clip(rint(
//      ((q1*s1)*wqd_c + bf_c)/s2 )))). Also CSS2[o] = s2*conv_s[o].
__global__ void k0L(float* __restrict__ ws) {
    const int c = blockIdx.x;
    const int t = threadIdx.x;                 // q1+127 in [0,255]; 255 unused
    const float s1 = fmaxf(ws[0] / QMAXF, EPSF);
    const float s2 = fmaxf(ws[1] / QMAXF, EPSF);
    const float wqd = ws[WQ_OFF + c];
    const float bf  = ws[BF_OFF + c];
    const float q1f = (float)(t - 127);
    const float xd  = __fmul_rn(q1f, s1);
    const float x2  = __fadd_rn(__fmul_rn(xd, wqd), bf);
    const float q2  = qclip(rintf(x2 / s2));
    const float a   = fmaxf(q2, 0.0f);
    ((u16*)(ws + LUT_OFF))[(c << 8) + t] = bf16bits(a);
    if (c == 0 && t < COUT)
        ws[CSS2_OFF + t] = __fmul_rn(s2, ws[CS_OFF + t]);
}

// stage one tile (X: 32p x 64k via LUT from preloaded regs; W: 128o x 64k from regs)
__device__ __forceinline__ void stage32(u16* __restrict__ Xs, u16* __restrict__ Wt,
                                        const float* __restrict__ xr8,
                                        const s16x8* __restrict__ wreg,
                                        int t, int ck, double rinv,
                                        const u16* __restrict__ lut) {
    const int p = t & 31, kh = t >> 5;
    u32 pk[4];
    #pragma unroll
    for (int jj = 0; jj < 4; ++jj) {
        const int c0 = ck + kh * 8 + 2 * jj;
        // exact-quotient via f64 mul: matches f32 correctly-rounded divide
        const int q1a = (int)rintf((float)((double)xr8[2 * jj] * rinv));
        const int q1b = (int)rintf((float)((double)xr8[2 * jj + 1] * rinv));
        const u32 lo = lut[(c0 << 8) + 127 + q1a];
        const u32 hi = lut[((c0 + 1) << 8) + 127 + q1b];
        pk[jj] = lo | (hi << 16);
    }
    uint4 v; v.x = pk[0]; v.y = pk[1]; v.z = pk[2]; v.w = pk[3];
    *(uint4*)&Xs[p * 64 + (((kh + p + (p >> 3)) & 7) * 8)] = v;
    #pragma unroll
    for (int ps = 0; ps < 4; ++ps) {
        const int o = ps * 32 + (t >> 3);
        *(s16x8*)&Wt[o * 64 + ((((t & 7) + o + (o >> 3)) & 7) * 8)] = wreg[ps];
    }
}

// K3: bf16-MFMA integer GEMM, 32-pixel tiles (3136 blocks), single-buffer LDS.
// ALL x for the block preloaded into registers up front (no in-loop global
// loads); LUT-based activation transform; W prefetched per K-step.
__global__ __launch_bounds__(256) void k3_mfma(const float* __restrict__ x,
                                               float* __restrict__ ws) {
    __shared__ __align__(16) u16 Xs[32 * 64];
    __shared__ __align__(16) u16 Wt[128 * 64];
    __shared__ float Css2s[COUT];
    __shared__ float red[4];

    const int t   = threadIdx.x;
    const int b   = blockIdx.x / 98;
    const int hw0 = (blockIdx.x % 98) * 32;
    const int l   = t & 63, w = t >> 6;
    const int wc  = w * 32;                    // wave cout base (4 waves x 32)

    const float s1 = fmaxf(ws[0] / QMAXF, EPSF);
    const double rinv = 1.0 / (double)s1;
    const u16* lut = (const u16*)(ws + LUT_OFF);
    const u16* cwb = (const u16*)(ws + CWB_OFF);

    if (t < COUT) Css2s[t] = ws[CSS2_OFF + t];

    const int p  = t & 31;        // staging pixel
    const int kh = t >> 5;        // staging 8-k group
    const float* xb = x + (size_t)b * CIN * HW + hw0 + p;

    // preload ALL x for this block: 32 channels' worth per thread
    float xr[32];
    #pragma unroll
    for (int it = 0; it < 4; ++it)
        #pragma unroll
        for (int j = 0; j < 8; ++j)
            xr[it * 8 + j] = xb[(it * 64 + kh * 8 + j) * HW];

    s16x8 wreg[4];
    #pragma unroll
    for (int ps = 0; ps < 4; ++ps)
        wreg[ps] = *(const s16x8*)(cwb + (ps * 32 + (t >> 3)) * CIN + (t & 7) * 8);

    f32x4 acc[2][2];
    #pragma unroll
    for (int m = 0; m < 2; ++m)
        #pragma unroll
        for (int n = 0; n < 2; ++n) acc[m][n] = (f32x4)0.0f;

    stage32(Xs, Wt, &xr[0], wreg, t, 0, rinv, lut);
    __syncthreads();

    #pragma unroll
    for (int it = 0; it < 4; ++it) {
        const int ckn = (it + 1) * 64;
        if (it < 3) {       // prefetch next W K-tile into regs (overlaps MFMA)
            #pragma unroll
            for (int ps = 0; ps < 4; ++ps)
                wreg[ps] = *(const s16x8*)(cwb + (ps * 32 + (t >> 3)) * CIN + ckn + (t & 7) * 8);
        }
        #pragma unroll
        for (int ks = 0; ks < 2; ++ks) {
            const int ch = ks * 4 + (l >> 4);
            s16x8 xf[2], wfr[2];
            #pragma unroll
            for (int n = 0; n < 2; ++n) {
                const int pp = n * 16 + (l & 15);
                xf[n] = *(const s16x8*)&Xs[pp * 64 + (((ch + pp + (pp >> 3)) & 7) * 8)];
            }
            #pragma unroll
            for (int m = 0; m < 2; ++m) {
                const int o = wc + m * 16 + (l & 15);
                wfr[m] = *(const s16x8*)&Wt[o * 64 + (((ch + o + (o >> 3)) & 7) * 8)];
            }
            #pragma unroll
            for (int m = 0; m < 2; ++m)
                #pragma unroll
                for (int n = 0; n < 2; ++n)
                    acc[m][n] = __builtin_amdgcn_mfma_f32_16x16x32_bf16(
                                    wfr[m], xf[n], acc[m][n], 0, 0, 0);
        }
        if (it < 3) {
            __syncthreads();
            stage32(Xs, Wt, &xr[(it + 1) * 8], wreg, t, ckn, rinv, lut);
            __syncthreads();
        }
    }

    // epilogue: scale exact int sums; write y; block max
    float mloc = 0.0f;
    #pragma unroll
    for (int m = 0; m < 2; ++m) {
        #pragma unroll
        for (int n = 0; n < 2; ++n) {
            const int pix = hw0 + n * 16 + (l & 15);
            #pragma unroll
            for (int r = 0; r < 4; ++r) {
                const int o = wc + m * 16 + (l >> 4) * 4 + r;
                const float val = __fmul_rn(acc[m][n][r], Css2s[o]);
                ws[Y_OFF + ((size_t)(b * COUT + o)) * HW + pix] = val;
                mloc = fmaxf(mloc, fabsf(val));
            }
        }
    }
    block_max_atomic(mloc, red, (u32*)ws + 2);
}

// K4: integer-domain 2x2 average pool (grid-stride); pooled -> d_out; abs-max -> ws[3]
__global__ void k4_pool(float* __restrict__ ws, float* __restrict__ out) {
    __shared__ float red[4];
    const float s3 = fmaxf(ws[2] / QMAXF, EPSF);
    float mloc = 0.0f;
    const int nq2 = NPOOL / 2;
    for (int pp = blockIdx.x * 256 + threadIdx.x; pp < nq2;
         pp += POOL_BLOCKS * 256) {
        const int j2  = pp % 14;
        const int tmp = pp / 14;
        const int i   = tmp % 28;
        const int bo  = tmp / 28;
        const float* yb = ws + Y_OFF + (size_t)bo * HW + (2 * i) * W_ + 4 * j2;
        const float4 r0 = *(const float4*)yb;
        const float4 r1 = *(const float4*)(yb + W_);
        const float q00 = qclip(rintf(r0.x / s3)), q01 = qclip(rintf(r0.y / s3));
        const float q02 = qclip(rintf(r0.z / s3)), q03 = qclip(rintf(r0.w / s3));
        const float q10 = qclip(rintf(r1.x / s3)), q11 = qclip(rintf(r1.y / s3));
        const float q12 = qclip(rintf(r1.z / s3)), q13 = qclip(rintf(r1.w / s3));
        const float p0 = __fmul_rn(__fmul_rn((q00 + q01) + (q10 + q11), 0.25f), s3);
        const float p1 = __fmul_rn(__fmul_rn((q02 + q03) + (q12 + q13), 0.25f), s3);
        float2 pv; pv.x = p0; pv.y = p1;
        *(float2*)(out + (size_t)bo * 784 + i * 28 + 2 * j2) = pv;
        mloc = fmaxf(mloc, fmaxf(fabsf(p0), fabsf(p1)));
    }
    block_max_atomic(mloc, red, (u32*)ws + 3);
}

// K5: final fake-quant in place (float4 grid-stride) + write act_s scalar
__global__ void k5_final(float* __restrict__ out, const float* __restrict__ ws) {
    const float s4 = fmaxf(ws[3] / QMAXF, EPSF);
    const int n4 = NPOOL / 4;
    for (int i = blockIdx.x * 256 + threadIdx.x; i < n4; i += 3136 * 256) {
        float4 v = *(float4*)(out + 4 * (size_t)i);
        v.x = __fmul_rn(qclip(rintf(v.x / s4)), s4);
        v.y = __fmul_rn(qclip(rintf(v.y / s4)), s4);
        v.z = __fmul_rn(qclip(rintf(v.z / s4)), s4);
        v.w = __fmul_rn(qclip(rintf(v.w / s4)), s4);
        *(float4*)(out + 4 * (size_t)i) = v;
    }
    if (blockIdx.x == 0 && threadIdx.x == 0) out[NPOOL] = s4;
}

extern "C" void kernel_launch(void* const* d_in, const int* in_sizes, int n_in,
                              void* d_out, int out_size, void* d_ws, size_t ws_size,
                              hipStream_t stream) {
    const float* x     = (const float*)d_in[0];
    const float* gamma = (const float*)d_in[1];
    const float* beta  = (const float*)d_in[2];
    const float* mean  = (const float*)d_in[3];
    const float* var   = (const float*)d_in[4];
    const float* cw    = (const float*)d_in[5];
    float* out = (float*)d_out;
    float* ws  = (float*)d_ws;

    hipLaunchKernelGGL(k0w, dim3(COUT + 1), dim3(256), 0, stream, cw, ws);
    hipLaunchKernelGGL(k1_minmax, dim3(32 * CIN), dim3(256), 0, stream, x, ws);
    hipLaunchKernelGGL(k0b, dim3(1), dim3(256), 0, stream, gamma, beta, mean, var, ws);
    hipLaunchKernelGGL(k0L, dim3(256), dim3(256), 0, stream, ws);
    hipLaunchKernelGGL(k3_mfma, dim3(3136), dim3(256), 0, stream, x, ws);
    hipLaunchKernelGGL(k4_pool, dim3(POOL_BLOCKS), dim3(256), 0, stream, ws, out);
    hipLaunchKernelGGL(k5_final, dim3(3136), dim3(256), 0, stream, out, ws);
}